// Round 9
// baseline (1667.429 us; speedup 1.0000x reference)
//
#include <hip/hip_runtime.h>
#include <math.h>

#define N_TOK 65536
#define HID   256
#define FFDIM 1024
#define QKVM  768
#define EPS_LN 1e-5f
#define RBLOCKS 256

typedef __bf16 bf16x8 __attribute__((ext_vector_type(8)));
typedef float  f32x4  __attribute__((ext_vector_type(4)));
typedef unsigned short u16x8 __attribute__((ext_vector_type(8)));

__device__ __forceinline__ float gelu_f(float x) {
    return 0.5f * x * (1.0f + erff(x * 0.70710678118654752f));
}
__device__ __forceinline__ float bf2f(unsigned short u) {
    return __uint_as_float(((unsigned int)u) << 16);
}
__device__ __forceinline__ unsigned short f2bf(float f) {
    unsigned int x = __float_as_uint(f);
    unsigned int r = ((x >> 16) & 1u) + 0x7fffu;
    return (unsigned short)((x + r) >> 16);
}
__device__ __forceinline__ void gload16(const void* g, void* l) {
    __builtin_amdgcn_global_load_lds(
        (const __attribute__((address_space(1))) void*)g,
        (__attribute__((address_space(3))) void*)l, 16, 0, 0);
}

// ------- weight fp32 [L,K,M] -> bf16 transposed [L][moff+M][K], row-scaled by g
__global__ __launch_bounds__(256) void wconv(
    const float* __restrict__ src, const float* __restrict__ g,
    unsigned short* __restrict__ dst,
    const int K, const int M, const size_t dstLS, const int moff)
{
    const int l = blockIdx.z;
    __shared__ float t[32][33];
    const int r  = threadIdx.x >> 3;
    const int c0 = (threadIdx.x & 7) * 4;
    const int bk = blockIdx.x * 32;
    const int bm = blockIdx.y * 32;
    float4 v4 = *(const float4*)(src + (size_t)l * K * M + (size_t)(bk + r) * M + bm + c0);
    if (g) {
        const float gv = g[(size_t)l * K + bk + r];
        v4.x *= gv; v4.y *= gv; v4.z *= gv; v4.w *= gv;
    }
    t[r][c0] = v4.x; t[r][c0+1] = v4.y; t[r][c0+2] = v4.z; t[r][c0+3] = v4.w;
    __syncthreads();
    ushort4 o;
    o.x = f2bf(t[c0+0][r]);
    o.y = f2bf(t[c0+1][r]);
    o.z = f2bf(t[c0+2][r]);
    o.w = f2bf(t[c0+3][r]);
    *(ushort4*)(dst + (size_t)l * dstLS + (size_t)(moff + bm + r) * K + bk + c0) = o;
}

__global__ __launch_bounds__(256) void biasfold(
    const float* __restrict__ W, const float* __restrict__ bias,
    const float* __restrict__ bvec, float* __restrict__ outb,
    const int K, const int M, const size_t outLS, const int moff)
{
    const int l = blockIdx.y;
    const int m = blockIdx.x * 256 + threadIdx.x;
    float acc = bias[(size_t)l * M + m];
    const float* Wl = W + (size_t)l * K * M;
    const float* bv = bvec + (size_t)l * K;
    for (int k = 0; k < K; ++k) acc = fmaf(bv[k], Wl[(size_t)k * M + m], acc);
    outb[(size_t)l * outLS + moff + m] = acc;
}

__global__ __launch_bounds__(256) void colsum(
    const unsigned short* __restrict__ wt, float* __restrict__ S, const int M)
{
    const int l = blockIdx.y;
    const int j = blockIdx.x * 256 + threadIdx.x;
    const unsigned short* rowp = wt + (size_t)l * M * HID + (size_t)j * HID;
    float s = 0.f;
    for (int k = 0; k < HID; k += 8) {
        const u16x8 u = *(const u16x8*)(rowp + k);
        #pragma unroll
        for (int t = 0; t < 8; ++t) s += bf2f(u[t]);
    }
    S[(size_t)l * M + j] = s;
}

__global__ __launch_bounds__(256) void cast_bf(
    const float* __restrict__ x, unsigned short* __restrict__ hb)
{
    const size_t i = ((size_t)blockIdx.x * 256 + threadIdx.x) * 8;
    const float4 a = *(const float4*)(x + i);
    const float4 b = *(const float4*)(x + i + 4);
    u16x8 o;
    o[0] = f2bf(a.x); o[1] = f2bf(a.y); o[2] = f2bf(a.z); o[3] = f2bf(a.w);
    o[4] = f2bf(b.x); o[5] = f2bf(b.y); o[6] = f2bf(b.z); o[7] = f2bf(b.w);
    *(u16x8*)(hb + i) = o;
}

__global__ __launch_bounds__(256) void stats_bf(
    const unsigned short* __restrict__ hb,
    float* __restrict__ mean, float* __restrict__ rstd)
{
    const int row  = blockIdx.x * 4 + (threadIdx.x >> 6);
    const int lane = threadIdx.x & 63;
    const ushort4 u = *(const ushort4*)(hb + (size_t)row * HID + lane * 4);
    const float x0 = bf2f(u.x), x1 = bf2f(u.y), x2 = bf2f(u.z), x3 = bf2f(u.w);
    float s  = x0 + x1 + x2 + x3;
    float s2 = fmaf(x0, x0, fmaf(x1, x1, fmaf(x2, x2, x3 * x3)));
    #pragma unroll
    for (int off = 32; off > 0; off >>= 1) {
        s  += __shfl_xor(s, off, 64);
        s2 += __shfl_xor(s2, off, 64);
    }
    if (lane == 0) {
        const float m   = s * (1.0f / HID);
        const float var = fmaxf(s2 * (1.0f / HID) - m * m, 0.f);
        mean[row] = m;
        rstd[row] = rsqrtf(var + EPS_LN);
    }
}

// ------- single-buffered BK=64 MFMA GEMM, 5 blocks/CU (TLP-first) -------------
// 128x128 tile; global_load_lds staging; XOR-64 swizzle chunk^(row&7) on 128B
// rows (round-5-verified: 0 bank conflicts). Epilogue-LN / GELU / res options.
// v = LNEP ? (acc - mean[row]*S[col])*rstd[row] + Bias[col] : acc + Bias[col]
template<int K, bool LNEP, bool GELU_EP, bool RES, bool OUTF32>
__global__ __launch_bounds__(256, 5) void gemm_sb(
    const unsigned short* __restrict__ A, const int lda,
    const unsigned short* __restrict__ Wt,
    const float* __restrict__ Bias, const float* __restrict__ S,
    const float* __restrict__ mean, const float* __restrict__ rstd,
    const unsigned short* __restrict__ res, const int ldr,
    void* __restrict__ C, const int ldc)
{
    constexpr int KT = K / 64;
    __shared__ __align__(16) unsigned short Abuf[128 * 64];   // 16 KB
    __shared__ __align__(16) unsigned short Bbuf[128 * 64];   // 16 KB
    const int tid  = threadIdx.x;
    const int lane = tid & 63;
    const int wv   = tid >> 6;
    const int bn = blockIdx.x << 7;   // col block (x fastest)
    const int bm = blockIdx.y << 7;
    // staging: wave wv covers tile rows [wv*32, wv*32+32), 4 instrs x 8 rows.
    const int srow = (wv << 5) + (lane >> 3);
    const int schk = (lane & 7) ^ ((lane >> 3) & 7);   // inverse-swizzled source
    const char* Asrc = (const char*)(A  + (size_t)(bm + srow) * lda) + schk * 16;
    const char* Bsrc = (const char*)(Wt + (size_t)(bn + srow) * K)   + schk * 16;

    const int lrow = lane & 15;
    const int kgrp = lane >> 4;
    const int wr = (wv >> 1) << 6;
    const int wc = (wv & 1) << 6;

    f32x4 acc[4][4];
    #pragma unroll
    for (int i = 0; i < 4; ++i)
        #pragma unroll
        for (int j = 0; j < 4; ++j)
            acc[i][j] = (f32x4){0.f, 0.f, 0.f, 0.f};

    for (int kt = 0; kt < KT; ++kt) {
        {   // stage both tiles (8 x gload16 per wave)
            const char* as = Asrc + kt * 128;   // 64 bf16 = 128 B per row-slice
            const char* bs = Bsrc + kt * 128;
            char* ad = (char*)Abuf + (wv << 12);
            char* bd = (char*)Bbuf + (wv << 12);
            #pragma unroll
            for (int i = 0; i < 4; ++i) {
                gload16(as + (size_t)(i * 8) * (lda * 2), ad + i * 1024);
                gload16(bs + (size_t)(i * 8) * (K * 2),   bd + i * 1024);
            }
        }
        __syncthreads();    // drains vmcnt(0): data visible
        #pragma unroll
        for (int ks = 0; ks < 2; ++ks) {
            bf16x8 bfv[4];
            #pragma unroll
            for (int ni = 0; ni < 4; ++ni) {
                const int cr = wc + ni * 16 + lrow;
                const int p = ((ks << 2) + kgrp) ^ (cr & 7);
                bfv[ni] = *(const bf16x8*)((const char*)Bbuf + cr * 128 + p * 16);
            }
            #pragma unroll
            for (int mi = 0; mi < 4; ++mi) {
                const int lr = wr + mi * 16 + lrow;
                const int p = ((ks << 2) + kgrp) ^ (lr & 7);
                const bf16x8 af = *(const bf16x8*)((const char*)Abuf + lr * 128 + p * 16);
                #pragma unroll
                for (int ni = 0; ni < 4; ++ni)
                    acc[mi][ni] = __builtin_amdgcn_mfma_f32_16x16x32_bf16(
                        af, bfv[ni], acc[mi][ni], 0, 0, 0);
            }
        }
        __syncthreads();    // reads done before next stage overwrites
    }
    // epilogue: D[row=(lane>>4)*4+r][col=lane&15] per 16x16 fragment
    #pragma unroll
    for (int mi = 0; mi < 4; ++mi) {
        #pragma unroll
        for (int ni = 0; ni < 4; ++ni) {
            const int col = bn + wc + ni * 16 + lrow;
            const float bv = Bias[col];
            const float sv = LNEP ? S[col] : 0.f;
            #pragma unroll
            for (int r = 0; r < 4; ++r) {
                const int row = bm + wr + mi * 16 + kgrp * 4 + r;
                float v = acc[mi][ni][r];
                if (LNEP) v = (v - mean[row] * sv) * rstd[row] + bv;
                else      v += bv;
                if (RES)  v += bf2f(res[(size_t)row * ldr + col]);
                if (GELU_EP) v = gelu_f(v);
                if (OUTF32) ((float*)C)[(size_t)row * ldc + col] = v;
                else ((unsigned short*)C)[(size_t)row * ldc + col] = f2bf(v);
            }
        }
    }
}

// ------- stage-1 reduction over packed qkv [N][768] ---------------------------
__global__ __launch_bounds__(256) void reduce_kernel(
    const unsigned short* __restrict__ qkv,
    float* __restrict__ pkv, float* __restrict__ pks,
    float* __restrict__ psq, float* __restrict__ psk)
{
    const int b   = blockIdx.x;
    const int tid = threadIdx.x;
    const int cg  = tid & 31;
    const int ro  = tid >> 5;
    const int c   = cg * 8;
    const int r0  = b * (N_TOK / RBLOCKS);
    float kv[8] = {}, ks[8] = {};
    float sq = 0.f, sk = 0.f;
    #pragma unroll 4
    for (int i = 0; i < (N_TOK / RBLOCKS) / 8; ++i) {
        const size_t base = (size_t)(r0 + ro + i * 8) * QKVM;
        const u16x8 q8 = *(const u16x8*)(qkv + base + c);
        const u16x8 k8 = *(const u16x8*)(qkv + base + 256 + c);
        const u16x8 v8 = *(const u16x8*)(qkv + base + 512 + c);
        #pragma unroll
        for (int j = 0; j < 8; ++j) {
            const float qf = bf2f(q8[j]), kf = bf2f(k8[j]), vf = bf2f(v8[j]);
            kv[j] = fmaf(kf, vf, kv[j]);
            ks[j] += kf;
            sq = fmaf(qf, qf, sq);
            sk = fmaf(kf, kf, sk);
        }
    }
    __shared__ float lkv[8][256];
    __shared__ float lks[8][256];
    #pragma unroll
    for (int j = 0; j < 8; ++j) { lkv[ro][c + j] = kv[j]; lks[ro][c + j] = ks[j]; }
    __syncthreads();
    float skv = 0.f, sks = 0.f;
    #pragma unroll
    for (int r = 0; r < 8; ++r) { skv += lkv[r][tid]; sks += lks[r][tid]; }
    pkv[(size_t)b * HID + tid] = skv;
    pks[(size_t)b * HID + tid] = sks;
    #pragma unroll
    for (int off = 32; off > 0; off >>= 1) {
        sq += __shfl_down(sq, off, 64);
        sk += __shfl_down(sk, off, 64);
    }
    __shared__ float s1[4], s2[4];
    if ((tid & 63) == 0) { s1[tid >> 6] = sq; s2[tid >> 6] = sk; }
    __syncthreads();
    if (tid == 0) {
        psq[b] = s1[0] + s1[1] + s1[2] + s1[3];
        psk[b] = s2[0] + s2[1] + s2[2] + s2[3];
    }
}

__global__ __launch_bounds__(256) void finalize_kernel(
    const float* __restrict__ pkv, const float* __restrict__ pks,
    const float* __restrict__ psq, const float* __restrict__ psk,
    float* __restrict__ kvsum, float* __restrict__ kssum, float* __restrict__ scal)
{
    const int c = threadIdx.x;
    float kv = 0.f, ks = 0.f;
    #pragma unroll 4
    for (int b = 0; b < RBLOCKS; ++b) {
        kv += pkv[(size_t)b * HID + c];
        ks += pks[(size_t)b * HID + c];
    }
    kvsum[c] = kv;
    kssum[c] = ks;
    float sq = 0.f, sk = 0.f;
    for (int b = c; b < RBLOCKS; b += 256) { sq += psq[b]; sk += psk[b]; }
    #pragma unroll
    for (int off = 32; off > 0; off >>= 1) {
        sq += __shfl_down(sq, off, 64);
        sk += __shfl_down(sk, off, 64);
    }
    __shared__ float s1[4], s2[4];
    if ((c & 63) == 0) { s1[c >> 6] = sq; s2[c >> 6] = sk; }
    __syncthreads();
    if (c == 0) {
        const float SQ = s1[0] + s1[1] + s1[2] + s1[3];
        const float SK = s2[0] + s2[1] + s2[2] + s2[3];
        scal[0] = rsqrtf(SQ * SK);
    }
}

__global__ __launch_bounds__(256) void attn_kernel(
    unsigned short* __restrict__ qkv,
    const float* __restrict__ kvsum, const float* __restrict__ kssum,
    const float* __restrict__ scal)
{
    const int row  = blockIdx.x * 8 + (threadIdx.x >> 5);
    const int lane = threadIdx.x & 31;
    const int c = lane * 8;
    const size_t base = (size_t)row * QKVM;
    const float inv = scal[0];
    const u16x8 q8 = *(const u16x8*)(qkv + base + c);
    const u16x8 v8 = *(const u16x8*)(qkv + base + 512 + c);
    float qf[8];
    float dot = 0.f;
    #pragma unroll
    for (int j = 0; j < 8; ++j) {
        qf[j] = bf2f(q8[j]);
        dot = fmaf(qf[j], kssum[c + j], dot);
    }
    dot += __shfl_xor(dot, 1, 4);
    dot += __shfl_xor(dot, 2, 4);
    const float rden = 1.0f / fmaf(dot, inv, (float)N_TOK);
    u16x8 o;
    #pragma unroll
    for (int j = 0; j < 8; ++j) {
        const float num = fmaf(qf[j] * kvsum[c + j], inv, bf2f(v8[j]) * (float)N_TOK);
        o[j] = f2bf(num * rden);
    }
    *(u16x8*)(qkv + base + c) = o;
}

extern "C" void kernel_launch(void* const* d_in, const int* in_sizes, int n_in,
                              void* d_out, int out_size, void* d_ws, size_t ws_size,
                              hipStream_t stream) {
    const float* x    = (const float*)d_in[0];
    const float* Wq   = (const float*)d_in[1];
    const float* bq   = (const float*)d_in[2];
    const float* Wk   = (const float*)d_in[3];
    const float* bk   = (const float*)d_in[4];
    const float* Wv   = (const float*)d_in[5];
    const float* bv   = (const float*)d_in[6];
    const float* Wh   = (const float*)d_in[7];
    const float* bh   = (const float*)d_in[8];
    const float* g1kv = (const float*)d_in[9];
    const float* b1kv = (const float*)d_in[10];
    const float* g1q  = (const float*)d_in[11];
    const float* b1q  = (const float*)d_in[12];
    const float* Wf1  = (const float*)d_in[13];
    const float* bf1  = (const float*)d_in[14];
    const float* Wf2  = (const float*)d_in[15];
    const float* bf2  = (const float*)d_in[16];
    const float* g2   = (const float*)d_in[17];
    const float* b2   = (const float*)d_in[18];
    float* out = (float*)d_out;

    // ---- workspace (~200 MiB; limit ~256 MiB) ----
    char* p = (char*)d_ws;
    const size_t nh = (size_t)N_TOK * HID;
    unsigned short* hb   = (unsigned short*)p; p += nh * 2;       // 32 MiB
    unsigned short* hpre = (unsigned short*)p; p += nh * 2;       // 32 MiB
    unsigned short* act  = (unsigned short*)p;                    // 128 MiB
    unsigned short* qkv  = act;                                   // overlay 96 MiB
    p += nh * 8;
    float* meanb = (float*)p; p += N_TOK * sizeof(float);
    float* rstdb = (float*)p; p += N_TOK * sizeof(float);
    unsigned short* wtqkv = (unsigned short*)p; p += (size_t)3 * QKVM * HID * 2;
    unsigned short* wth   = (unsigned short*)p; p += (size_t)3 * HID * HID * 2;
    unsigned short* wtf1  = (unsigned short*)p; p += (size_t)3 * FFDIM * HID * 2;
    unsigned short* wtf2  = (unsigned short*)p; p += (size_t)3 * HID * FFDIM * 2;
    float* bqkv = (float*)p; p += (size_t)3 * QKVM * sizeof(float);
    float* bf1f = (float*)p; p += (size_t)3 * FFDIM * sizeof(float);
    float* Sqkv = (float*)p; p += (size_t)3 * QKVM * sizeof(float);
    float* Sf1  = (float*)p; p += (size_t)3 * FFDIM * sizeof(float);
    float* pkv  = (float*)p; p += (size_t)RBLOCKS * HID * sizeof(float);
    float* pks  = (float*)p; p += (size_t)RBLOCKS * HID * sizeof(float);
    float* psq  = (float*)p; p += RBLOCKS * sizeof(float);
    float* psk  = (float*)p; p += RBLOCKS * sizeof(float);
    float* kvs  = (float*)p; p += HID * sizeof(float);
    float* kss  = (float*)p; p += HID * sizeof(float);
    float* scal = (float*)p; p += 256;

    const size_t qkvLS = (size_t)QKVM * HID;
    wconv<<<dim3(8, 8, 3),  256, 0, stream>>>(Wq,  g1q,  wtqkv, HID, HID, qkvLS, 0);
    wconv<<<dim3(8, 8, 3),  256, 0, stream>>>(Wk,  g1kv, wtqkv, HID, HID, qkvLS, 256);
    wconv<<<dim3(8, 8, 3),  256, 0, stream>>>(Wv,  g1kv, wtqkv, HID, HID, qkvLS, 512);
    wconv<<<dim3(8, 8, 3),  256, 0, stream>>>(Wh,  nullptr, wth, HID, HID, (size_t)HID * HID, 0);
    wconv<<<dim3(8, 32, 3), 256, 0, stream>>>(Wf1, g2,   wtf1, HID, FFDIM, (size_t)FFDIM * HID, 0);
    wconv<<<dim3(32, 8, 3), 256, 0, stream>>>(Wf2, nullptr, wtf2, FFDIM, HID, (size_t)HID * FFDIM, 0);
    colsum<<<dim3(3, 3), 256, 0, stream>>>(wtqkv, Sqkv, QKVM);
    colsum<<<dim3(4, 3), 256, 0, stream>>>(wtf1,  Sf1,  FFDIM);
    biasfold<<<dim3(1, 3), 256, 0, stream>>>(Wq,  bq,  b1q,  bqkv, HID, HID, QKVM, 0);
    biasfold<<<dim3(1, 3), 256, 0, stream>>>(Wk,  bk,  b1kv, bqkv, HID, HID, QKVM, 256);
    biasfold<<<dim3(1, 3), 256, 0, stream>>>(Wv,  bv,  b1kv, bqkv, HID, HID, QKVM, 512);
    biasfold<<<dim3(4, 3), 256, 0, stream>>>(Wf1, bf1, b2,   bf1f, HID, FFDIM, FFDIM, 0);
    cast_bf<<<nh / (256 * 8), 256, 0, stream>>>(x, hb);

    const dim3 gQKV(QKVM / 128, N_TOK / 128);   // (6, 512)
    const dim3 gH(HID / 128, N_TOK / 128);      // (2, 512)
    const dim3 gF1(FFDIM / 128, N_TOK / 128);   // (8, 512)

    for (int l = 0; l < 3; ++l) {
        stats_bf<<<N_TOK / 4, 256, 0, stream>>>(hb, meanb, rstdb);
        // QKV: epilogue-LN, A = hb -> packed qkv [N][768]
        gemm_sb<HID, true, false, false, false><<<gQKV, 256, 0, stream>>>(
            hb, HID, wtqkv + l * qkvLS, bqkv + l * QKVM, Sqkv + l * QKVM,
            meanb, rstdb, nullptr, 0, qkv, QKVM);
        reduce_kernel<<<RBLOCKS, 256, 0, stream>>>(qkv, pkv, pks, psq, psk);
        finalize_kernel<<<1, 256, 0, stream>>>(pkv, pks, psq, psk, kvs, kss, scal);
        attn_kernel<<<N_TOK / 8, 256, 0, stream>>>(qkv, kvs, kss, scal);
        // H: A = attn (q slice of qkv, lda 768) + res hb -> hpre
        gemm_sb<HID, false, false, true, false><<<gH, 256, 0, stream>>>(
            qkv, QKVM, wth + (size_t)l * HID * HID, bh + (size_t)l * HID, nullptr,
            nullptr, nullptr, hb, HID, hpre, HID);
        stats_bf<<<N_TOK / 4, 256, 0, stream>>>(hpre, meanb, rstdb);
        // FFN1: epilogue-LN + GELU -> act
        gemm_sb<HID, true, true, false, false><<<gF1, 256, 0, stream>>>(
            hpre, HID, wtf1 + (size_t)l * FFDIM * HID, bf1f + (size_t)l * FFDIM,
            Sf1 + (size_t)l * FFDIM, meanb, rstdb, nullptr, 0, act, FFDIM);
        // FFN2: + res(hpre) -> next hb (bf16) or final d_out (fp32)
        if (l < 2)
            gemm_sb<FFDIM, false, false, true, false><<<gH, 256, 0, stream>>>(
                act, FFDIM, wtf2 + (size_t)l * HID * FFDIM, bf2 + (size_t)l * HID,
                nullptr, nullptr, nullptr, hpre, HID, hb, HID);
        else
            gemm_sb<FFDIM, false, false, true, true><<<gH, 256, 0, stream>>>(
                act, FFDIM, wtf2 + (size_t)l * HID * FFDIM, bf2 + (size_t)l * HID,
                nullptr, nullptr, nullptr, hpre, HID, out, HID);
    }
}

// Round 10
// 1185.429 us; speedup vs baseline: 1.4066x; 1.4066x over previous
//
#include <hip/hip_runtime.h>
#include <math.h>

#define N_TOK 65536
#define HID   256
#define FFDIM 1024
#define QKVM  768
#define EPS_LN 1e-5f
#define RBLOCKS 256

typedef __bf16 bf16x8 __attribute__((ext_vector_type(8)));
typedef float  f32x4  __attribute__((ext_vector_type(4)));
typedef unsigned short u16x8 __attribute__((ext_vector_type(8)));

__device__ __forceinline__ float gelu_f(float x) {
    return 0.5f * x * (1.0f + erff(x * 0.70710678118654752f));
}
__device__ __forceinline__ float bf2f(unsigned short u) {
    return __uint_as_float(((unsigned int)u) << 16);
}
__device__ __forceinline__ unsigned short f2bf(float f) {
    unsigned int x = __float_as_uint(f);
    unsigned int r = ((x >> 16) & 1u) + 0x7fffu;
    return (unsigned short)((x + r) >> 16);
}

// ------- weight fp32 [L,K,M] -> bf16 transposed [L][moff+M][K], row-scaled by g
__global__ __launch_bounds__(256) void wconv(
    const float* __restrict__ src, const float* __restrict__ g,
    unsigned short* __restrict__ dst,
    const int K, const int M, const size_t dstLS, const int moff)
{
    const int l = blockIdx.z;
    __shared__ float t[32][33];
    const int r  = threadIdx.x >> 3;
    const int c0 = (threadIdx.x & 7) * 4;
    const int bk = blockIdx.x * 32;
    const int bm = blockIdx.y * 32;
    float4 v4 = *(const float4*)(src + (size_t)l * K * M + (size_t)(bk + r) * M + bm + c0);
    if (g) {
        const float gv = g[(size_t)l * K + bk + r];
        v4.x *= gv; v4.y *= gv; v4.z *= gv; v4.w *= gv;
    }
    t[r][c0] = v4.x; t[r][c0+1] = v4.y; t[r][c0+2] = v4.z; t[r][c0+3] = v4.w;
    __syncthreads();
    ushort4 o;
    o.x = f2bf(t[c0+0][r]);
    o.y = f2bf(t[c0+1][r]);
    o.z = f2bf(t[c0+2][r]);
    o.w = f2bf(t[c0+3][r]);
    *(ushort4*)(dst + (size_t)l * dstLS + (size_t)(moff + bm + r) * K + bk + c0) = o;
}

__global__ __launch_bounds__(256) void biasfold(
    const float* __restrict__ W, const float* __restrict__ bias,
    const float* __restrict__ bvec, float* __restrict__ outb,
    const int K, const int M, const size_t outLS, const int moff)
{
    const int l = blockIdx.y;
    const int m = blockIdx.x * 256 + threadIdx.x;
    float acc = bias[(size_t)l * M + m];
    const float* Wl = W + (size_t)l * K * M;
    const float* bv = bvec + (size_t)l * K;
    for (int k = 0; k < K; ++k) acc = fmaf(bv[k], Wl[(size_t)k * M + m], acc);
    outb[(size_t)l * outLS + moff + m] = acc;
}

__global__ __launch_bounds__(256) void colsum(
    const unsigned short* __restrict__ wt, float* __restrict__ S, const int M)
{
    const int l = blockIdx.y;
    const int j = blockIdx.x * 256 + threadIdx.x;
    const unsigned short* rowp = wt + (size_t)l * M * HID + (size_t)j * HID;
    float s = 0.f;
    for (int k = 0; k < HID; k += 8) {
        const u16x8 u = *(const u16x8*)(rowp + k);
        #pragma unroll
        for (int t = 0; t < 8; ++t) s += bf2f(u[t]);
    }
    S[(size_t)l * M + j] = s;
}

__global__ __launch_bounds__(256) void cast_bf(
    const float* __restrict__ x, unsigned short* __restrict__ hb)
{
    const size_t i = ((size_t)blockIdx.x * 256 + threadIdx.x) * 8;
    const float4 a = *(const float4*)(x + i);
    const float4 b = *(const float4*)(x + i + 4);
    u16x8 o;
    o[0] = f2bf(a.x); o[1] = f2bf(a.y); o[2] = f2bf(a.z); o[3] = f2bf(a.w);
    o[4] = f2bf(b.x); o[5] = f2bf(b.y); o[6] = f2bf(b.z); o[7] = f2bf(b.w);
    *(u16x8*)(hb + i) = o;
}

__global__ __launch_bounds__(256) void stats_bf(
    const unsigned short* __restrict__ hb,
    float* __restrict__ mean, float* __restrict__ rstd)
{
    const int row  = blockIdx.x * 4 + (threadIdx.x >> 6);
    const int lane = threadIdx.x & 63;
    const ushort4 u = *(const ushort4*)(hb + (size_t)row * HID + lane * 4);
    const float x0 = bf2f(u.x), x1 = bf2f(u.y), x2 = bf2f(u.z), x3 = bf2f(u.w);
    float s  = x0 + x1 + x2 + x3;
    float s2 = fmaf(x0, x0, fmaf(x1, x1, fmaf(x2, x2, x3 * x3)));
    #pragma unroll
    for (int off = 32; off > 0; off >>= 1) {
        s  += __shfl_xor(s, off, 64);
        s2 += __shfl_xor(s2, off, 64);
    }
    if (lane == 0) {
        const float m   = s * (1.0f / HID);
        const float var = fmaxf(s2 * (1.0f / HID) - m * m, 0.f);
        mean[row] = m;
        rstd[row] = rsqrtf(var + EPS_LN);
    }
}

// ------- R4-core bf16 MFMA GEMM: 128x128 tile, BK=32, reg-staged dbuf ---------
// LDS rows padded to 40 elems (80B; ~2-way bank alias, accepted — R4-measured
// best). Grid x = row-tiles (fastest) -> B panel L2/L3-resident.
// Epilogue: v = LNEP ? (acc - mean[row]*S[col])*rstd[row] + Bias[col]
//                    : acc + Bias[col];  then +res, gelu, store bf16/fp32.
template<int K, bool LNEP, bool GELU_EP, bool RES, bool OUTF32>
__global__ __launch_bounds__(256, 2) void gemm_rs(
    const unsigned short* __restrict__ A, const int lda,
    const unsigned short* __restrict__ Wt,
    const float* __restrict__ Bias, const float* __restrict__ S,
    const float* __restrict__ mean, const float* __restrict__ rstd,
    const unsigned short* __restrict__ res, const int ldr,
    void* __restrict__ C, const int ldc)
{
    constexpr int KT  = K / 32;
    constexpr int LDT = 40;
    __shared__ __align__(16) unsigned short Abuf[2][128 * LDT];
    __shared__ __align__(16) unsigned short Bbuf[2][128 * LDT];
    const int tid = threadIdx.x;
    const int bm = blockIdx.x << 7;   // row block (x fastest)
    const int bn = blockIdx.y << 7;   // col block
    const int lr = tid >> 2;          // staging row 0..63
    const int lk = (tid & 3) << 3;    // staging k-chunk 0,8,16,24
    const unsigned short* Ag = A  + (size_t)(bm + lr) * lda + lk;
    const unsigned short* Bg = Wt + (size_t)(bn + lr) * K   + lk;
    const int lds_off = lr * LDT + lk;

    const int lane = tid & 63;
    const int wv   = tid >> 6;
    const int wr   = (wv >> 1) << 6;
    const int wc   = (wv & 1) << 6;
    const int lrow = lane & 15;
    const int kgrp = lane >> 4;

    f32x4 acc[4][4];
    #pragma unroll
    for (int i = 0; i < 4; ++i)
        #pragma unroll
        for (int j = 0; j < 4; ++j)
            acc[i][j] = (f32x4){0.f, 0.f, 0.f, 0.f};

    u16x8 ra0, ra1, rb0, rb1;
    auto gload = [&](int kt) {
        const unsigned short* a = Ag + kt * 32;
        const unsigned short* b = Bg + kt * 32;
        ra0 = *(const u16x8*)a;
        ra1 = *(const u16x8*)(a + (size_t)64 * lda);
        rb0 = *(const u16x8*)b;
        rb1 = *(const u16x8*)(b + (size_t)64 * K);
    };
    auto lstore = [&](int buf) {
        *(u16x8*)&Abuf[buf][lds_off]            = ra0;
        *(u16x8*)&Abuf[buf][lds_off + 64 * LDT] = ra1;
        *(u16x8*)&Bbuf[buf][lds_off]            = rb0;
        *(u16x8*)&Bbuf[buf][lds_off + 64 * LDT] = rb1;
    };

    gload(0);
    lstore(0);
    __syncthreads();
    for (int kt = 0; kt < KT; ++kt) {
        const int cur = kt & 1;
        if (kt + 1 < KT) gload(kt + 1);
        bf16x8 af[4], bfr[4];
        #pragma unroll
        for (int mi = 0; mi < 4; ++mi)
            af[mi] = *(const bf16x8*)&Abuf[cur][(wr + mi * 16 + lrow) * LDT + kgrp * 8];
        #pragma unroll
        for (int ni = 0; ni < 4; ++ni)
            bfr[ni] = *(const bf16x8*)&Bbuf[cur][(wc + ni * 16 + lrow) * LDT + kgrp * 8];
        #pragma unroll
        for (int mi = 0; mi < 4; ++mi)
            #pragma unroll
            for (int ni = 0; ni < 4; ++ni)
                acc[mi][ni] = __builtin_amdgcn_mfma_f32_16x16x32_bf16(
                    af[mi], bfr[ni], acc[mi][ni], 0, 0, 0);
        if (kt + 1 < KT) {
            __syncthreads();
            lstore(cur ^ 1);
            __syncthreads();
        }
    }
    // epilogue: D[row=(lane>>4)*4+r][col=lane&15] per 16x16 fragment
    #pragma unroll
    for (int mi = 0; mi < 4; ++mi) {
        #pragma unroll
        for (int ni = 0; ni < 4; ++ni) {
            const int col = bn + wc + ni * 16 + lrow;
            const float bv = Bias[col];
            const float sv = LNEP ? S[col] : 0.f;
            #pragma unroll
            for (int r = 0; r < 4; ++r) {
                const int row = bm + wr + mi * 16 + kgrp * 4 + r;
                float v = acc[mi][ni][r];
                if (LNEP) v = (v - mean[row] * sv) * rstd[row] + bv;
                else      v += bv;
                if (RES)  v += bf2f(res[(size_t)row * ldr + col]);
                if (GELU_EP) v = gelu_f(v);
                if (OUTF32) ((float*)C)[(size_t)row * ldc + col] = v;
                else ((unsigned short*)C)[(size_t)row * ldc + col] = f2bf(v);
            }
        }
    }
}

// ------- stage-1 reduction over packed qkv [N][768] ---------------------------
__global__ __launch_bounds__(256) void reduce_kernel(
    const unsigned short* __restrict__ qkv,
    float* __restrict__ pkv, float* __restrict__ pks,
    float* __restrict__ psq, float* __restrict__ psk)
{
    const int b   = blockIdx.x;
    const int tid = threadIdx.x;
    const int cg  = tid & 31;
    const int ro  = tid >> 5;
    const int c   = cg * 8;
    const int r0  = b * (N_TOK / RBLOCKS);
    float kv[8] = {}, ks[8] = {};
    float sq = 0.f, sk = 0.f;
    #pragma unroll 4
    for (int i = 0; i < (N_TOK / RBLOCKS) / 8; ++i) {
        const size_t base = (size_t)(r0 + ro + i * 8) * QKVM;
        const u16x8 q8 = *(const u16x8*)(qkv + base + c);
        const u16x8 k8 = *(const u16x8*)(qkv + base + 256 + c);
        const u16x8 v8 = *(const u16x8*)(qkv + base + 512 + c);
        #pragma unroll
        for (int j = 0; j < 8; ++j) {
            const float qf = bf2f(q8[j]), kf = bf2f(k8[j]), vf = bf2f(v8[j]);
            kv[j] = fmaf(kf, vf, kv[j]);
            ks[j] += kf;
            sq = fmaf(qf, qf, sq);
            sk = fmaf(kf, kf, sk);
        }
    }
    __shared__ float lkv[8][256];
    __shared__ float lks[8][256];
    #pragma unroll
    for (int j = 0; j < 8; ++j) { lkv[ro][c + j] = kv[j]; lks[ro][c + j] = ks[j]; }
    __syncthreads();
    float skv = 0.f, sks = 0.f;
    #pragma unroll
    for (int r = 0; r < 8; ++r) { skv += lkv[r][tid]; sks += lks[r][tid]; }
    pkv[(size_t)b * HID + tid] = skv;
    pks[(size_t)b * HID + tid] = sks;
    #pragma unroll
    for (int off = 32; off > 0; off >>= 1) {
        sq += __shfl_down(sq, off, 64);
        sk += __shfl_down(sk, off, 64);
    }
    __shared__ float s1[4], s2[4];
    if ((tid & 63) == 0) { s1[tid >> 6] = sq; s2[tid >> 6] = sk; }
    __syncthreads();
    if (tid == 0) {
        psq[b] = s1[0] + s1[1] + s1[2] + s1[3];
        psk[b] = s2[0] + s2[1] + s2[2] + s2[3];
    }
}

__global__ __launch_bounds__(256) void finalize_kernel(
    const float* __restrict__ pkv, const float* __restrict__ pks,
    const float* __restrict__ psq, const float* __restrict__ psk,
    float* __restrict__ kvsum, float* __restrict__ kssum, float* __restrict__ scal)
{
    const int c = threadIdx.x;
    float kv = 0.f, ks = 0.f;
    #pragma unroll 4
    for (int b = 0; b < RBLOCKS; ++b) {
        kv += pkv[(size_t)b * HID + c];
        ks += pks[(size_t)b * HID + c];
    }
    kvsum[c] = kv;
    kssum[c] = ks;
    float sq = 0.f, sk = 0.f;
    for (int b = c; b < RBLOCKS; b += 256) { sq += psq[b]; sk += psk[b]; }
    #pragma unroll
    for (int off = 32; off > 0; off >>= 1) {
        sq += __shfl_down(sq, off, 64);
        sk += __shfl_down(sk, off, 64);
    }
    __shared__ float s1[4], s2[4];
    if ((c & 63) == 0) { s1[c >> 6] = sq; s2[c >> 6] = sk; }
    __syncthreads();
    if (c == 0) {
        const float SQ = s1[0] + s1[1] + s1[2] + s1[3];
        const float SK = s2[0] + s2[1] + s2[2] + s2[3];
        scal[0] = rsqrtf(SQ * SK);
    }
}

__global__ __launch_bounds__(256) void attn_kernel(
    unsigned short* __restrict__ qkv,
    const float* __restrict__ kvsum, const float* __restrict__ kssum,
    const float* __restrict__ scal)
{
    const int row  = blockIdx.x * 8 + (threadIdx.x >> 5);
    const int lane = threadIdx.x & 31;
    const int c = lane * 8;
    const size_t base = (size_t)row * QKVM;
    const float inv = scal[0];
    const u16x8 q8 = *(const u16x8*)(qkv + base + c);
    const u16x8 v8 = *(const u16x8*)(qkv + base + 512 + c);
    float qf[8];
    float dot = 0.f;
    #pragma unroll
    for (int j = 0; j < 8; ++j) {
        qf[j] = bf2f(q8[j]);
        dot = fmaf(qf[j], kssum[c + j], dot);
    }
    dot += __shfl_xor(dot, 1, 4);
    dot += __shfl_xor(dot, 2, 4);
    const float rden = 1.0f / fmaf(dot, inv, (float)N_TOK);
    u16x8 o;
    #pragma unroll
    for (int j = 0; j < 8; ++j) {
        const float num = fmaf(qf[j] * kvsum[c + j], inv, bf2f(v8[j]) * (float)N_TOK);
        o[j] = f2bf(num * rden);
    }
    *(u16x8*)(qkv + base + c) = o;
}

extern "C" void kernel_launch(void* const* d_in, const int* in_sizes, int n_in,
                              void* d_out, int out_size, void* d_ws, size_t ws_size,
                              hipStream_t stream) {
    const float* x    = (const float*)d_in[0];
    const float* Wq   = (const float*)d_in[1];
    const float* bq   = (const float*)d_in[2];
    const float* Wk   = (const float*)d_in[3];
    const float* bk   = (const float*)d_in[4];
    const float* Wv   = (const float*)d_in[5];
    const float* bv   = (const float*)d_in[6];
    const float* Wh   = (const float*)d_in[7];
    const float* bh   = (const float*)d_in[8];
    const float* g1kv = (const float*)d_in[9];
    const float* b1kv = (const float*)d_in[10];
    const float* g1q  = (const float*)d_in[11];
    const float* b1q  = (const float*)d_in[12];
    const float* Wf1  = (const float*)d_in[13];
    const float* bf1  = (const float*)d_in[14];
    const float* Wf2  = (const float*)d_in[15];
    const float* bf2  = (const float*)d_in[16];
    const float* g2   = (const float*)d_in[17];
    const float* b2   = (const float*)d_in[18];
    float* out = (float*)d_out;

    // ---- workspace (~200 MiB; limit ~256 MiB) ----
    char* p = (char*)d_ws;
    const size_t nh = (size_t)N_TOK * HID;
    unsigned short* hb   = (unsigned short*)p; p += nh * 2;       // 32 MiB
    unsigned short* hpre = (unsigned short*)p; p += nh * 2;       // 32 MiB
    unsigned short* act  = (unsigned short*)p;                    // 128 MiB
    unsigned short* qkv  = act;                                   // overlay 96 MiB
    p += nh * 8;
    float* meanb = (float*)p; p += N_TOK * sizeof(float);
    float* rstdb = (float*)p; p += N_TOK * sizeof(float);
    unsigned short* wtqkv = (unsigned short*)p; p += (size_t)3 * QKVM * HID * 2;
    unsigned short* wth   = (unsigned short*)p; p += (size_t)3 * HID * HID * 2;
    unsigned short* wtf1  = (unsigned short*)p; p += (size_t)3 * FFDIM * HID * 2;
    unsigned short* wtf2  = (unsigned short*)p; p += (size_t)3 * HID * FFDIM * 2;
    float* bqkv = (float*)p; p += (size_t)3 * QKVM * sizeof(float);
    float* bf1f = (float*)p; p += (size_t)3 * FFDIM * sizeof(float);
    float* Sqkv = (float*)p; p += (size_t)3 * QKVM * sizeof(float);
    float* Sf1  = (float*)p; p += (size_t)3 * FFDIM * sizeof(float);
    float* pkv  = (float*)p; p += (size_t)RBLOCKS * HID * sizeof(float);
    float* pks  = (float*)p; p += (size_t)RBLOCKS * HID * sizeof(float);
    float* psq  = (float*)p; p += RBLOCKS * sizeof(float);
    float* psk  = (float*)p; p += RBLOCKS * sizeof(float);
    float* kvs  = (float*)p; p += HID * sizeof(float);
    float* kss  = (float*)p; p += HID * sizeof(float);
    float* scal = (float*)p; p += 256;

    const size_t qkvLS = (size_t)QKVM * HID;
    wconv<<<dim3(8, 8, 3),  256, 0, stream>>>(Wq,  g1q,  wtqkv, HID, HID, qkvLS, 0);
    wconv<<<dim3(8, 8, 3),  256, 0, stream>>>(Wk,  g1kv, wtqkv, HID, HID, qkvLS, 256);
    wconv<<<dim3(8, 8, 3),  256, 0, stream>>>(Wv,  g1kv, wtqkv, HID, HID, qkvLS, 512);
    wconv<<<dim3(8, 8, 3),  256, 0, stream>>>(Wh,  nullptr, wth, HID, HID, (size_t)HID * HID, 0);
    wconv<<<dim3(8, 32, 3), 256, 0, stream>>>(Wf1, g2,   wtf1, HID, FFDIM, (size_t)FFDIM * HID, 0);
    wconv<<<dim3(32, 8, 3), 256, 0, stream>>>(Wf2, nullptr, wtf2, FFDIM, HID, (size_t)HID * FFDIM, 0);
    colsum<<<dim3(3, 3), 256, 0, stream>>>(wtqkv, Sqkv, QKVM);
    colsum<<<dim3(4, 3), 256, 0, stream>>>(wtf1,  Sf1,  FFDIM);
    biasfold<<<dim3(1, 3), 256, 0, stream>>>(Wq,  bq,  b1q,  bqkv, HID, HID, QKVM, 0);
    biasfold<<<dim3(1, 3), 256, 0, stream>>>(Wk,  bk,  b1kv, bqkv, HID, HID, QKVM, 256);
    biasfold<<<dim3(1, 3), 256, 0, stream>>>(Wv,  bv,  b1kv, bqkv, HID, HID, QKVM, 512);
    biasfold<<<dim3(4, 3), 256, 0, stream>>>(Wf1, bf1, b2,   bf1f, HID, FFDIM, FFDIM, 0);
    cast_bf<<<nh / (256 * 8), 256, 0, stream>>>(x, hb);

    // grids: x = row-tiles (fastest), y = col-tiles  (R4 orientation)
    const dim3 gQKV(N_TOK / 128, QKVM / 128);   // (512, 6)
    const dim3 gH(N_TOK / 128, HID / 128);      // (512, 2)
    const dim3 gF1(N_TOK / 128, FFDIM / 128);   // (512, 8)

    for (int l = 0; l < 3; ++l) {
        stats_bf<<<N_TOK / 4, 256, 0, stream>>>(hb, meanb, rstdb);
        // QKV: epilogue-LN, A = hb -> packed qkv [N][768]
        gemm_rs<HID, true, false, false, false><<<gQKV, 256, 0, stream>>>(
            hb, HID, wtqkv + l * qkvLS, bqkv + l * QKVM, Sqkv + l * QKVM,
            meanb, rstdb, nullptr, 0, qkv, QKVM);
        reduce_kernel<<<RBLOCKS, 256, 0, stream>>>(qkv, pkv, pks, psq, psk);
        finalize_kernel<<<1, 256, 0, stream>>>(pkv, pks, psq, psk, kvs, kss, scal);
        attn_kernel<<<N_TOK / 8, 256, 0, stream>>>(qkv, kvs, kss, scal);
        // H: A = attn (q slice of qkv, lda 768) + res hb -> hpre
        gemm_rs<HID, false, false, true, false><<<gH, 256, 0, stream>>>(
            qkv, QKVM, wth + (size_t)l * HID * HID, bh + (size_t)l * HID, nullptr,
            nullptr, nullptr, hb, HID, hpre, HID);
        stats_bf<<<N_TOK / 4, 256, 0, stream>>>(hpre, meanb, rstdb);
        // FFN1: epilogue-LN + GELU -> act
        gemm_rs<HID, true, true, false, false><<<gF1, 256, 0, stream>>>(
            hpre, HID, wtf1 + (size_t)l * FFDIM * HID, bf1f + (size_t)l * FFDIM,
            Sf1 + (size_t)l * FFDIM, meanb, rstdb, nullptr, 0, act, FFDIM);
        // FFN2: + res(hpre) -> next hb (bf16) or final d_out (fp32)
        if (l < 2)
            gemm_rs<FFDIM, false, false, true, false><<<gH, 256, 0, stream>>>(
                act, FFDIM, wtf2 + (size_t)l * HID * FFDIM, bf2 + (size_t)l * HID,
                nullptr, nullptr, nullptr, hpre, HID, hb, HID);
        else
            gemm_rs<FFDIM, false, false, true, true><<<gH, 256, 0, stream>>>(
                act, FFDIM, wtf2 + (size_t)l * HID * FFDIM, bf2 + (size_t)l * HID,
                nullptr, nullptr, nullptr, hpre, HID, out, HID);
    }
}

// Round 11
// 1128.139 us; speedup vs baseline: 1.4780x; 1.0508x over previous
//
#include <hip/hip_runtime.h>
#include <math.h>

#define N_TOK 65536
#define HID   256
#define FFDIM 1024
#define QKVM  768
#define EPS_LN 1e-5f
#define RBLOCKS 256

typedef __bf16 bf16x8 __attribute__((ext_vector_type(8)));
typedef float  f32x4  __attribute__((ext_vector_type(4)));
typedef unsigned short u16x8 __attribute__((ext_vector_type(8)));

__device__ __forceinline__ float gelu_f(float x) {
    return 0.5f * x * (1.0f + erff(x * 0.70710678118654752f));
}
__device__ __forceinline__ float bf2f(unsigned short u) {
    return __uint_as_float(((unsigned int)u) << 16);
}
__device__ __forceinline__ unsigned short f2bf(float f) {
    unsigned int x = __float_as_uint(f);
    unsigned int r = ((x >> 16) & 1u) + 0x7fffu;
    return (unsigned short)((x + r) >> 16);
}

// ------- weight fp32 [L,K,M] -> bf16 transposed [L][moff+M][K], row-scaled by g
__global__ __launch_bounds__(256) void wconv(
    const float* __restrict__ src, const float* __restrict__ g,
    unsigned short* __restrict__ dst,
    const int K, const int M, const size_t dstLS, const int moff)
{
    const int l = blockIdx.z;
    __shared__ float t[32][33];
    const int r  = threadIdx.x >> 3;
    const int c0 = (threadIdx.x & 7) * 4;
    const int bk = blockIdx.x * 32;
    const int bm = blockIdx.y * 32;
    float4 v4 = *(const float4*)(src + (size_t)l * K * M + (size_t)(bk + r) * M + bm + c0);
    if (g) {
        const float gv = g[(size_t)l * K + bk + r];
        v4.x *= gv; v4.y *= gv; v4.z *= gv; v4.w *= gv;
    }
    t[r][c0] = v4.x; t[r][c0+1] = v4.y; t[r][c0+2] = v4.z; t[r][c0+3] = v4.w;
    __syncthreads();
    ushort4 o;
    o.x = f2bf(t[c0+0][r]);
    o.y = f2bf(t[c0+1][r]);
    o.z = f2bf(t[c0+2][r]);
    o.w = f2bf(t[c0+3][r]);
    *(ushort4*)(dst + (size_t)l * dstLS + (size_t)(moff + bm + r) * K + bk + c0) = o;
}

__global__ __launch_bounds__(256) void biasfold(
    const float* __restrict__ W, const float* __restrict__ bias,
    const float* __restrict__ bvec, float* __restrict__ outb,
    const int K, const int M, const size_t outLS, const int moff)
{
    const int l = blockIdx.y;
    const int m = blockIdx.x * 256 + threadIdx.x;
    float acc = bias[(size_t)l * M + m];
    const float* Wl = W + (size_t)l * K * M;
    const float* bv = bvec + (size_t)l * K;
    for (int k = 0; k < K; ++k) acc = fmaf(bv[k], Wl[(size_t)k * M + m], acc);
    outb[(size_t)l * outLS + moff + m] = acc;
}

__global__ __launch_bounds__(256) void colsum(
    const unsigned short* __restrict__ wt, float* __restrict__ S, const int M)
{
    const int l = blockIdx.y;
    const int j = blockIdx.x * 256 + threadIdx.x;
    const unsigned short* rowp = wt + (size_t)l * M * HID + (size_t)j * HID;
    float s = 0.f;
    for (int k = 0; k < HID; k += 8) {
        const u16x8 u = *(const u16x8*)(rowp + k);
        #pragma unroll
        for (int t = 0; t < 8; ++t) s += bf2f(u[t]);
    }
    S[(size_t)l * M + j] = s;
}

__global__ __launch_bounds__(256) void cast_bf(
    const float* __restrict__ x, unsigned short* __restrict__ hb)
{
    const size_t i = ((size_t)blockIdx.x * 256 + threadIdx.x) * 8;
    const float4 a = *(const float4*)(x + i);
    const float4 b = *(const float4*)(x + i + 4);
    u16x8 o;
    o[0] = f2bf(a.x); o[1] = f2bf(a.y); o[2] = f2bf(a.z); o[3] = f2bf(a.w);
    o[4] = f2bf(b.x); o[5] = f2bf(b.y); o[6] = f2bf(b.z); o[7] = f2bf(b.w);
    *(u16x8*)(hb + i) = o;
}

__global__ __launch_bounds__(256) void stats_bf(
    const unsigned short* __restrict__ hb,
    float* __restrict__ mean, float* __restrict__ rstd)
{
    const int row  = blockIdx.x * 4 + (threadIdx.x >> 6);
    const int lane = threadIdx.x & 63;
    const ushort4 u = *(const ushort4*)(hb + (size_t)row * HID + lane * 4);
    const float x0 = bf2f(u.x), x1 = bf2f(u.y), x2 = bf2f(u.z), x3 = bf2f(u.w);
    float s  = x0 + x1 + x2 + x3;
    float s2 = fmaf(x0, x0, fmaf(x1, x1, fmaf(x2, x2, x3 * x3)));
    #pragma unroll
    for (int off = 32; off > 0; off >>= 1) {
        s  += __shfl_xor(s, off, 64);
        s2 += __shfl_xor(s2, off, 64);
    }
    if (lane == 0) {
        const float m   = s * (1.0f / HID);
        const float var = fmaxf(s2 * (1.0f / HID) - m * m, 0.f);
        mean[row] = m;
        rstd[row] = rsqrtf(var + EPS_LN);
    }
}

// ------- R4-core bf16 MFMA GEMM + group/XCD swizzle + single-barrier dbuf -----
// 128x128 tile, BK=32, reg-staged double-buffered LDS (rows padded to 40).
// Block map: groups of 8 row-tiles x nCT col-tiles, ROW-FASTEST inside a group
// -> consecutive IDs round-robin XCDs, so each XCD keeps ONE A-row-panel (hot
// in its L2, reused across its col-tiles) + all B-panels (small).
// Dbuf needs only ONE barrier/iter: reads of buf b in iter k-1 are >=1 barrier
// ahead of the store to buf b in iter k+1.
template<int K, bool LNEP, bool GELU_EP, bool RES, bool OUTF32>
__global__ __launch_bounds__(256, 2) void gemm_rs(
    const unsigned short* __restrict__ A, const int lda,
    const unsigned short* __restrict__ Wt,
    const float* __restrict__ Bias, const float* __restrict__ S,
    const float* __restrict__ mean, const float* __restrict__ rstd,
    const unsigned short* __restrict__ res, const int ldr,
    void* __restrict__ C, const int ldc, const int nCT)
{
    constexpr int KT  = K / 32;
    constexpr int LDT = 40;
    __shared__ __align__(16) unsigned short Abuf[2][128 * LDT];
    __shared__ __align__(16) unsigned short Bbuf[2][128 * LDT];
    const int tid = threadIdx.x;
    const int gsz = nCT << 3;
    const int grp = blockIdx.x / gsz;
    const int rem = blockIdx.x - grp * gsz;
    const int bm  = ((grp << 3) + (rem & 7)) << 7;   // row tile (fastest in group)
    const int bn  = (rem >> 3) << 7;                 // col tile
    const int lr = tid >> 2;          // staging row 0..63
    const int lk = (tid & 3) << 3;    // staging k-chunk 0,8,16,24
    const unsigned short* Ag = A  + (size_t)(bm + lr) * lda + lk;
    const unsigned short* Bg = Wt + (size_t)(bn + lr) * K   + lk;
    const int lds_off = lr * LDT + lk;

    const int lane = tid & 63;
    const int wv   = tid >> 6;
    const int wr   = (wv >> 1) << 6;
    const int wc   = (wv & 1) << 6;
    const int lrow = lane & 15;
    const int kgrp = lane >> 4;

    f32x4 acc[4][4];
    #pragma unroll
    for (int i = 0; i < 4; ++i)
        #pragma unroll
        for (int j = 0; j < 4; ++j)
            acc[i][j] = (f32x4){0.f, 0.f, 0.f, 0.f};

    u16x8 ra0, ra1, rb0, rb1;
    auto gload = [&](int kt) {
        const unsigned short* a = Ag + kt * 32;
        const unsigned short* b = Bg + kt * 32;
        ra0 = *(const u16x8*)a;
        ra1 = *(const u16x8*)(a + (size_t)64 * lda);
        rb0 = *(const u16x8*)b;
        rb1 = *(const u16x8*)(b + (size_t)64 * K);
    };
    auto lstore = [&](int buf) {
        *(u16x8*)&Abuf[buf][lds_off]            = ra0;
        *(u16x8*)&Abuf[buf][lds_off + 64 * LDT] = ra1;
        *(u16x8*)&Bbuf[buf][lds_off]            = rb0;
        *(u16x8*)&Bbuf[buf][lds_off + 64 * LDT] = rb1;
    };

    gload(0);
    lstore(0);
    __syncthreads();
    for (int kt = 0; kt < KT; ++kt) {
        const int cur = kt & 1;
        if (kt + 1 < KT) gload(kt + 1);
        bf16x8 af[4], bfr[4];
        #pragma unroll
        for (int mi = 0; mi < 4; ++mi)
            af[mi] = *(const bf16x8*)&Abuf[cur][(wr + mi * 16 + lrow) * LDT + kgrp * 8];
        #pragma unroll
        for (int ni = 0; ni < 4; ++ni)
            bfr[ni] = *(const bf16x8*)&Bbuf[cur][(wc + ni * 16 + lrow) * LDT + kgrp * 8];
        #pragma unroll
        for (int mi = 0; mi < 4; ++mi)
            #pragma unroll
            for (int ni = 0; ni < 4; ++ni)
                acc[mi][ni] = __builtin_amdgcn_mfma_f32_16x16x32_bf16(
                    af[mi], bfr[ni], acc[mi][ni], 0, 0, 0);
        if (kt + 1 < KT) {
            lstore(cur ^ 1);      // different buffer than all in-flight reads
            __syncthreads();      // single barrier per iteration
        }
    }
    // epilogue: D[row=(lane>>4)*4+r][col=lane&15] per 16x16 fragment
    #pragma unroll
    for (int mi = 0; mi < 4; ++mi) {
        #pragma unroll
        for (int ni = 0; ni < 4; ++ni) {
            const int col = bn + wc + ni * 16 + lrow;
            const float bv = Bias[col];
            const float sv = LNEP ? S[col] : 0.f;
            #pragma unroll
            for (int r = 0; r < 4; ++r) {
                const int row = bm + wr + mi * 16 + kgrp * 4 + r;
                float v = acc[mi][ni][r];
                if (LNEP) v = (v - mean[row] * sv) * rstd[row] + bv;
                else      v += bv;
                if (RES)  v += bf2f(res[(size_t)row * ldr + col]);
                if (GELU_EP) v = gelu_f(v);
                if (OUTF32) ((float*)C)[(size_t)row * ldc + col] = v;
                else ((unsigned short*)C)[(size_t)row * ldc + col] = f2bf(v);
            }
        }
    }
}

// ------- stage-1 reduction over packed qkv [N][768] ---------------------------
__global__ __launch_bounds__(256) void reduce_kernel(
    const unsigned short* __restrict__ qkv,
    float* __restrict__ pkv, float* __restrict__ pks,
    float* __restrict__ psq, float* __restrict__ psk)
{
    const int b   = blockIdx.x;
    const int tid = threadIdx.x;
    const int cg  = tid & 31;
    const int ro  = tid >> 5;
    const int c   = cg * 8;
    const int r0  = b * (N_TOK / RBLOCKS);
    float kv[8] = {}, ks[8] = {};
    float sq = 0.f, sk = 0.f;
    #pragma unroll 4
    for (int i = 0; i < (N_TOK / RBLOCKS) / 8; ++i) {
        const size_t base = (size_t)(r0 + ro + i * 8) * QKVM;
        const u16x8 q8 = *(const u16x8*)(qkv + base + c);
        const u16x8 k8 = *(const u16x8*)(qkv + base + 256 + c);
        const u16x8 v8 = *(const u16x8*)(qkv + base + 512 + c);
        #pragma unroll
        for (int j = 0; j < 8; ++j) {
            const float qf = bf2f(q8[j]), kf = bf2f(k8[j]), vf = bf2f(v8[j]);
            kv[j] = fmaf(kf, vf, kv[j]);
            ks[j] += kf;
            sq = fmaf(qf, qf, sq);
            sk = fmaf(kf, kf, sk);
        }
    }
    __shared__ float lkv[8][256];
    __shared__ float lks[8][256];
    #pragma unroll
    for (int j = 0; j < 8; ++j) { lkv[ro][c + j] = kv[j]; lks[ro][c + j] = ks[j]; }
    __syncthreads();
    float skv = 0.f, sks = 0.f;
    #pragma unroll
    for (int r = 0; r < 8; ++r) { skv += lkv[r][tid]; sks += lks[r][tid]; }
    pkv[(size_t)b * HID + tid] = skv;
    pks[(size_t)b * HID + tid] = sks;
    #pragma unroll
    for (int off = 32; off > 0; off >>= 1) {
        sq += __shfl_down(sq, off, 64);
        sk += __shfl_down(sk, off, 64);
    }
    __shared__ float s1[4], s2[4];
    if ((tid & 63) == 0) { s1[tid >> 6] = sq; s2[tid >> 6] = sk; }
    __syncthreads();
    if (tid == 0) {
        psq[b] = s1[0] + s1[1] + s1[2] + s1[3];
        psk[b] = s2[0] + s2[1] + s2[2] + s2[3];
    }
}

__global__ __launch_bounds__(256) void finalize_kernel(
    const float* __restrict__ pkv, const float* __restrict__ pks,
    const float* __restrict__ psq, const float* __restrict__ psk,
    float* __restrict__ kvsum, float* __restrict__ kssum, float* __restrict__ scal)
{
    const int c = threadIdx.x;
    float kv = 0.f, ks = 0.f;
    #pragma unroll 4
    for (int b = 0; b < RBLOCKS; ++b) {
        kv += pkv[(size_t)b * HID + c];
        ks += pks[(size_t)b * HID + c];
    }
    kvsum[c] = kv;
    kssum[c] = ks;
    float sq = 0.f, sk = 0.f;
    for (int b = c; b < RBLOCKS; b += 256) { sq += psq[b]; sk += psk[b]; }
    #pragma unroll
    for (int off = 32; off > 0; off >>= 1) {
        sq += __shfl_down(sq, off, 64);
        sk += __shfl_down(sk, off, 64);
    }
    __shared__ float s1[4], s2[4];
    if ((c & 63) == 0) { s1[c >> 6] = sq; s2[c >> 6] = sk; }
    __syncthreads();
    if (c == 0) {
        const float SQ = s1[0] + s1[1] + s1[2] + s1[3];
        const float SK = s2[0] + s2[1] + s2[2] + s2[3];
        scal[0] = rsqrtf(SQ * SK);
    }
}

__global__ __launch_bounds__(256) void attn_kernel(
    unsigned short* __restrict__ qkv,
    const float* __restrict__ kvsum, const float* __restrict__ kssum,
    const float* __restrict__ scal)
{
    const int row  = blockIdx.x * 8 + (threadIdx.x >> 5);
    const int lane = threadIdx.x & 31;
    const int c = lane * 8;
    const size_t base = (size_t)row * QKVM;
    const float inv = scal[0];
    const u16x8 q8 = *(const u16x8*)(qkv + base + c);
    const u16x8 v8 = *(const u16x8*)(qkv + base + 512 + c);
    float qf[8];
    float dot = 0.f;
    #pragma unroll
    for (int j = 0; j < 8; ++j) {
        qf[j] = bf2f(q8[j]);
        dot = fmaf(qf[j], kssum[c + j], dot);
    }
    dot += __shfl_xor(dot, 1, 4);
    dot += __shfl_xor(dot, 2, 4);
    const float rden = 1.0f / fmaf(dot, inv, (float)N_TOK);
    u16x8 o;
    #pragma unroll
    for (int j = 0; j < 8; ++j) {
        const float num = fmaf(qf[j] * kvsum[c + j], inv, bf2f(v8[j]) * (float)N_TOK);
        o[j] = f2bf(num * rden);
    }
    *(u16x8*)(qkv + base + c) = o;
}

extern "C" void kernel_launch(void* const* d_in, const int* in_sizes, int n_in,
                              void* d_out, int out_size, void* d_ws, size_t ws_size,
                              hipStream_t stream) {
    const float* x    = (const float*)d_in[0];
    const float* Wq   = (const float*)d_in[1];
    const float* bq   = (const float*)d_in[2];
    const float* Wk   = (const float*)d_in[3];
    const float* bk   = (const float*)d_in[4];
    const float* Wv   = (const float*)d_in[5];
    const float* bv   = (const float*)d_in[6];
    const float* Wh   = (const float*)d_in[7];
    const float* bh   = (const float*)d_in[8];
    const float* g1kv = (const float*)d_in[9];
    const float* b1kv = (const float*)d_in[10];
    const float* g1q  = (const float*)d_in[11];
    const float* b1q  = (const float*)d_in[12];
    const float* Wf1  = (const float*)d_in[13];
    const float* bf1  = (const float*)d_in[14];
    const float* Wf2  = (const float*)d_in[15];
    const float* bf2  = (const float*)d_in[16];
    const float* g2   = (const float*)d_in[17];
    const float* b2   = (const float*)d_in[18];
    float* out = (float*)d_out;

    // ---- workspace (~200 MiB; limit ~256 MiB) ----
    char* p = (char*)d_ws;
    const size_t nh = (size_t)N_TOK * HID;
    unsigned short* hb   = (unsigned short*)p; p += nh * 2;       // 32 MiB
    unsigned short* hpre = (unsigned short*)p; p += nh * 2;       // 32 MiB
    unsigned short* act  = (unsigned short*)p;                    // 128 MiB
    unsigned short* qkv  = act;                                   // overlay 96 MiB
    p += nh * 8;
    float* meanb = (float*)p; p += N_TOK * sizeof(float);
    float* rstdb = (float*)p; p += N_TOK * sizeof(float);
    unsigned short* wtqkv = (unsigned short*)p; p += (size_t)3 * QKVM * HID * 2;
    unsigned short* wth   = (unsigned short*)p; p += (size_t)3 * HID * HID * 2;
    unsigned short* wtf1  = (unsigned short*)p; p += (size_t)3 * FFDIM * HID * 2;
    unsigned short* wtf2  = (unsigned short*)p; p += (size_t)3 * HID * FFDIM * 2;
    float* bqkv = (float*)p; p += (size_t)3 * QKVM * sizeof(float);
    float* bf1f = (float*)p; p += (size_t)3 * FFDIM * sizeof(float);
    float* Sqkv = (float*)p; p += (size_t)3 * QKVM * sizeof(float);
    float* Sf1  = (float*)p; p += (size_t)3 * FFDIM * sizeof(float);
    float* pkv  = (float*)p; p += (size_t)RBLOCKS * HID * sizeof(float);
    float* pks  = (float*)p; p += (size_t)RBLOCKS * HID * sizeof(float);
    float* psq  = (float*)p; p += RBLOCKS * sizeof(float);
    float* psk  = (float*)p; p += RBLOCKS * sizeof(float);
    float* kvs  = (float*)p; p += HID * sizeof(float);
    float* kss  = (float*)p; p += HID * sizeof(float);
    float* scal = (float*)p; p += 256;

    const size_t qkvLS = (size_t)QKVM * HID;
    wconv<<<dim3(8, 8, 3),  256, 0, stream>>>(Wq,  g1q,  wtqkv, HID, HID, qkvLS, 0);
    wconv<<<dim3(8, 8, 3),  256, 0, stream>>>(Wk,  g1kv, wtqkv, HID, HID, qkvLS, 256);
    wconv<<<dim3(8, 8, 3),  256, 0, stream>>>(Wv,  g1kv, wtqkv, HID, HID, qkvLS, 512);
    wconv<<<dim3(8, 8, 3),  256, 0, stream>>>(Wh,  nullptr, wth, HID, HID, (size_t)HID * HID, 0);
    wconv<<<dim3(8, 32, 3), 256, 0, stream>>>(Wf1, g2,   wtf1, HID, FFDIM, (size_t)FFDIM * HID, 0);
    wconv<<<dim3(32, 8, 3), 256, 0, stream>>>(Wf2, nullptr, wtf2, FFDIM, HID, (size_t)HID * FFDIM, 0);
    colsum<<<dim3(3, 3), 256, 0, stream>>>(wtqkv, Sqkv, QKVM);
    colsum<<<dim3(4, 3), 256, 0, stream>>>(wtf1,  Sf1,  FFDIM);
    biasfold<<<dim3(1, 3), 256, 0, stream>>>(Wq,  bq,  b1q,  bqkv, HID, HID, QKVM, 0);
    biasfold<<<dim3(1, 3), 256, 0, stream>>>(Wk,  bk,  b1kv, bqkv, HID, HID, QKVM, 256);
    biasfold<<<dim3(1, 3), 256, 0, stream>>>(Wv,  bv,  b1kv, bqkv, HID, HID, QKVM, 512);
    biasfold<<<dim3(4, 3), 256, 0, stream>>>(Wf1, bf1, b2,   bf1f, HID, FFDIM, FFDIM, 0);
    cast_bf<<<nh / (256 * 8), 256, 0, stream>>>(x, hb);

    // 1D grids: nRowTiles * nColTiles blocks; group swizzle inside the kernel
    const int gQKV = (N_TOK / 128) * (QKVM / 128);   // 3072
    const int gH   = (N_TOK / 128) * (HID / 128);    // 1024
    const int gF1  = (N_TOK / 128) * (FFDIM / 128);  // 4096

    for (int l = 0; l < 3; ++l) {
        stats_bf<<<N_TOK / 4, 256, 0, stream>>>(hb, meanb, rstdb);
        // QKV: epilogue-LN, A = hb -> packed qkv [N][768]
        gemm_rs<HID, true, false, false, false><<<gQKV, 256, 0, stream>>>(
            hb, HID, wtqkv + l * qkvLS, bqkv + l * QKVM, Sqkv + l * QKVM,
            meanb, rstdb, nullptr, 0, qkv, QKVM, QKVM / 128);
        reduce_kernel<<<RBLOCKS, 256, 0, stream>>>(qkv, pkv, pks, psq, psk);
        finalize_kernel<<<1, 256, 0, stream>>>(pkv, pks, psq, psk, kvs, kss, scal);
        attn_kernel<<<N_TOK / 8, 256, 0, stream>>>(qkv, kvs, kss, scal);
        // H: A = attn (q slice of qkv, lda 768) + res hb -> hpre
        gemm_rs<HID, false, false, true, false><<<gH, 256, 0, stream>>>(
            qkv, QKVM, wth + (size_t)l * HID * HID, bh + (size_t)l * HID, nullptr,
            nullptr, nullptr, hb, HID, hpre, HID, HID / 128);
        stats_bf<<<N_TOK / 4, 256, 0, stream>>>(hpre, meanb, rstdb);
        // FFN1: epilogue-LN + GELU -> act
        gemm_rs<HID, true, true, false, false><<<gF1, 256, 0, stream>>>(
            hpre, HID, wtf1 + (size_t)l * FFDIM * HID, bf1f + (size_t)l * FFDIM,
            Sf1 + (size_t)l * FFDIM, meanb, rstdb, nullptr, 0, act, FFDIM, FFDIM / 128);
        // FFN2: + res(hpre) -> next hb (bf16) or final d_out (fp32)
        if (l < 2)
            gemm_rs<FFDIM, false, false, true, false><<<gH, 256, 0, stream>>>(
                act, FFDIM, wtf2 + (size_t)l * HID * FFDIM, bf2 + (size_t)l * HID,
                nullptr, nullptr, nullptr, hpre, HID, hb, HID, HID / 128);
        else
            gemm_rs<FFDIM, false, false, true, true><<<gH, 256, 0, stream>>>(
                act, FFDIM, wtf2 + (size_t)l * HID * FFDIM, bf2 + (size_t)l * HID,
                nullptr, nullptr, nullptr, hpre, HID, out, HID, HID / 128);
    }
}